// Round 2
// baseline (268.479 us; speedup 1.0000x reference)
//
#include <hip/hip_runtime.h>

typedef __attribute__((ext_vector_type(8))) short bf16x8;
typedef __attribute__((ext_vector_type(4))) float f32x4;

#define B_ 2
#define S_ 2048
#define H_ 16
#define D_ 64
#define BQ 64
#define BK 64
#define LDK 72   // padded LDS row length in bf16 elems (144 B, 16B-aligned)

__device__ __forceinline__ float b2f(ushort u) {
    union { unsigned int i; float f; } x; x.i = ((unsigned int)u) << 16; return x.f;
}
// fp32 -> bf16 bits, round-to-nearest-even (inputs are finite; no NaN path needed)
__device__ __forceinline__ ushort f2bs(float f) {
    union { float f; unsigned int u; } x; x.f = f;
    unsigned int r = (x.u + 0x7FFFu + ((x.u >> 16) & 1u)) >> 16;
    return (ushort)r;
}

// Dtype detector: even-indexed ushorts of a bf16 buffer are bf16(N(0,1)) values
// (~100% of |x| in [1e-3,100]); of an fp32 buffer they are low mantissa halves
// (uniform random bits, ~7% in range). Writes 1 = bf16, 0 = fp32.
__global__ void detect_kernel(const ushort* __restrict__ q, int* __restrict__ flag) {
    if (threadIdx.x == 0) {
        int good = 0;
        for (int i = 0; i < 128; ++i) {
            float v = b2f(q[2 * i]);
            float a = fabsf(v);
            if (a > 1e-3f && a < 100.0f) ++good;   // NaN fails both compares
        }
        *flag = (good >= 64) ? 1 : 0;
    }
}

__global__ __launch_bounds__(256, 2)
void fattn_kernel(const void* __restrict__ qg,
                  const void* __restrict__ kg,
                  const void* __restrict__ vg,
                  const void* __restrict__ maskg,
                  void* __restrict__ outg,
                  const int* __restrict__ flag)
{
    __shared__ ushort Ks[BK * LDK];        // K tile, row=key, col=d
    __shared__ ushort Vt[D_ * LDK];        // V tile transposed, row=d, col=key
    __shared__ ushort Ps[4][16 * LDK];     // per-wave P staging, row=m, col=key

    const bool isbf = (*flag != 0);        // wave-uniform

    const int qt = blockIdx.x;   // q-tile fastest -> consecutive blocks share (b,h) for K/V L2 reuse
    const int h  = blockIdx.y;
    const int b  = blockIdx.z;

    const int tid  = threadIdx.x;
    const int wave = tid >> 6;
    const int lane = tid & 63;
    const int quad = lane >> 4;
    const int l15  = lane & 15;

    const int qbase = qt * BQ;

    // Q fragments in A-operand layout: a[j] = Q[qrow][quad*8 + j] (+32 for second)
    const int qrow = qbase + wave * 16 + l15;
    const size_t qoff = ((size_t)(b * S_ + qrow) * H_ + h) * D_;
    bf16x8 qf0, qf1;
    if (isbf) {
        const ushort* qp = (const ushort*)qg + qoff;
        qf0 = *(const bf16x8*)(qp + 0  + quad * 8);
        qf1 = *(const bf16x8*)(qp + 32 + quad * 8);
    } else {
        const float* qp = (const float*)qg + qoff;
#pragma unroll
        for (int j = 0; j < 8; ++j) {
            qf0[j] = (short)f2bs(qp[quad * 8 + j]);
            qf1[j] = (short)f2bs(qp[32 + quad * 8 + j]);
        }
    }

    float m_r[4], l_r[4];
    f32x4 o_acc[4];
#pragma unroll
    for (int r = 0; r < 4; ++r) { m_r[r] = -1e30f; l_r[r] = 0.0f; }
#pragma unroll
    for (int t = 0; t < 4; ++t) o_acc[t] = (f32x4){0.f, 0.f, 0.f, 0.f};

    // staging mapping: one key per thread-mod-64, 16 d-elems per thread
    const int skey = tid & 63;
    const int sd0  = (tid >> 6) * 16;
    const size_t kvbase = ((size_t)(b * S_) * H_ + h) * D_;

    const float SCALE = 0.125f;   // 1/sqrt(64)

    for (int kt = 0; kt < S_ / BK; ++kt) {
        // ---- stage K (row-major) and V (transposed) into LDS, converting to bf16 ----
        {
            const size_t grow = kvbase + (size_t)(kt * BK + skey) * (H_ * D_) + sd0;
            bf16x8 k0v, k1v, v0v, v1v;
            if (isbf) {
                const ushort* kp = (const ushort*)kg + grow;
                const ushort* vp = (const ushort*)vg + grow;
                k0v = *(const bf16x8*)(kp);
                k1v = *(const bf16x8*)(kp + 8);
                v0v = *(const bf16x8*)(vp);
                v1v = *(const bf16x8*)(vp + 8);
            } else {
                const float* kp = (const float*)kg + grow;
                const float* vp = (const float*)vg + grow;
#pragma unroll
                for (int j = 0; j < 8; ++j) {
                    k0v[j] = (short)f2bs(kp[j]);
                    k1v[j] = (short)f2bs(kp[8 + j]);
                    v0v[j] = (short)f2bs(vp[j]);
                    v1v[j] = (short)f2bs(vp[8 + j]);
                }
            }
            *(bf16x8*)&Ks[skey * LDK + sd0]     = k0v;
            *(bf16x8*)&Ks[skey * LDK + sd0 + 8] = k1v;
#pragma unroll
            for (int j = 0; j < 8; ++j) {
                Vt[(sd0 + j)     * LDK + skey] = (ushort)v0v[j];
                Vt[(sd0 + 8 + j) * LDK + skey] = (ushort)v1v[j];
            }
        }
        __syncthreads();

        // ---- S = Q K^T for this wave's 16 rows x 64 keys ----
        f32x4 sacc[4];
#pragma unroll
        for (int t = 0; t < 4; ++t) {
            f32x4 acc = (f32x4){0.f, 0.f, 0.f, 0.f};
            bf16x8 kb0 = *(const bf16x8*)&Ks[(t * 16 + l15) * LDK + 0  + quad * 8];
            bf16x8 kb1 = *(const bf16x8*)&Ks[(t * 16 + l15) * LDK + 32 + quad * 8];
            acc = __builtin_amdgcn_mfma_f32_16x16x32_bf16(qf0, kb0, acc, 0, 0, 0);
            acc = __builtin_amdgcn_mfma_f32_16x16x32_bf16(qf1, kb1, acc, 0, 0, 0);
            sacc[t] = acc;
        }

        // ---- scale + additive mask (mask indexed by key) ----
        float sv[4][4];
#pragma unroll
        for (int t = 0; t < 4; ++t) {
            int kidx = kt * BK + t * 16 + l15;
            float mv = isbf ? b2f(((const ushort*)maskg)[(size_t)b * S_ + kidx])
                            : ((const float*)maskg)[(size_t)b * S_ + kidx];
#pragma unroll
            for (int r = 0; r < 4; ++r)
                sv[t][r] = fmaf(sacc[t][r], SCALE, mv);
        }

        // ---- online softmax (row = quad*4 + r; reduce across the quad's 16 lanes) ----
#pragma unroll
        for (int r = 0; r < 4; ++r) {
            float cm = fmaxf(fmaxf(sv[0][r], sv[1][r]), fmaxf(sv[2][r], sv[3][r]));
#pragma unroll
            for (int off = 1; off < 16; off <<= 1)
                cm = fmaxf(cm, __shfl_xor(cm, off, 64));
            float newm = fmaxf(m_r[r], cm);
            float alpha = __expf(m_r[r] - newm);
            float rs = 0.f;
#pragma unroll
            for (int t = 0; t < 4; ++t) {
                float p = __expf(sv[t][r] - newm);
                sv[t][r] = p;
                rs += p;
            }
#pragma unroll
            for (int off = 1; off < 16; off <<= 1)
                rs += __shfl_xor(rs, off, 64);
            l_r[r] = l_r[r] * alpha + rs;
            m_r[r] = newm;
#pragma unroll
            for (int t = 0; t < 4; ++t)
                o_acc[t][r] *= alpha;
        }

        // ---- P: C-layout regs -> A-layout via per-wave LDS round-trip ----
#pragma unroll
        for (int t = 0; t < 4; ++t)
#pragma unroll
            for (int r = 0; r < 4; ++r)
                Ps[wave][(quad * 4 + r) * LDK + t * 16 + l15] = f2bs(sv[t][r]);

        // in-wave RAW on LDS: ensure writes complete before fragment reads
        asm volatile("s_waitcnt lgkmcnt(0)" ::: "memory");

        // ---- O += P V ----
#pragma unroll
        for (int k0 = 0; k0 < 2; ++k0) {
            bf16x8 af = *(const bf16x8*)&Ps[wave][l15 * LDK + k0 * 32 + quad * 8];
#pragma unroll
            for (int t2 = 0; t2 < 4; ++t2) {
                bf16x8 bfv = *(const bf16x8*)&Vt[(t2 * 16 + l15) * LDK + k0 * 32 + quad * 8];
                o_acc[t2] = __builtin_amdgcn_mfma_f32_16x16x32_bf16(af, bfv, o_acc[t2], 0, 0, 0);
            }
        }
        __syncthreads();
    }

    // ---- epilogue: O / l, store in the output dtype ----
    const size_t obase = ((size_t)(b * S_ + qbase + wave * 16) * H_ + h) * D_;
#pragma unroll
    for (int r = 0; r < 4; ++r) {
        float inv = 1.0f / l_r[r];
        int row = quad * 4 + r;
#pragma unroll
        for (int t2 = 0; t2 < 4; ++t2) {
            int d = t2 * 16 + l15;
            float val = o_acc[t2][r] * inv;
            size_t off = obase + (size_t)row * (H_ * D_) + d;
            if (isbf) ((ushort*)outg)[off] = f2bs(val);
            else      ((float*)outg)[off]  = val;
        }
    }
}

extern "C" void kernel_launch(void* const* d_in, const int* in_sizes, int n_in,
                              void* d_out, int out_size, void* d_ws, size_t ws_size,
                              hipStream_t stream) {
    int* flag = (int*)d_ws;
    detect_kernel<<<1, 64, 0, stream>>>((const ushort*)d_in[0], flag);

    dim3 grid(S_ / BQ, H_, B_);   // q-tile fastest for K/V L2 reuse
    fattn_kernel<<<grid, dim3(256), 0, stream>>>(d_in[0], d_in[1], d_in[2], d_in[3],
                                                 d_out, flag);
}

// Round 3
// 175.614 us; speedup vs baseline: 1.5288x; 1.5288x over previous
//
#include <hip/hip_runtime.h>

// Round 3: S^T-formulation flash attention, fp32 in/out (proven r1/r2), bf16 MFMA compute.
//   St = K·Q^T via mfma_f32_16x16x32_bf16 (A=K row-major, B=Q row-major; free operand swap)
//   O^T = V^T·P^T via mfma_f32_16x16x16_bf16: St C-layout(key=quad*4+r, q=l15) IS the
//   x16 B-operand layout(k=quad*4+j, n=l15) -> P stays in registers, zero LDS round-trip.
//   Per-lane softmax state (q=l15): 2+2 shuffles per tile instead of 64.

typedef __attribute__((ext_vector_type(8))) short bf16x8;
typedef __attribute__((ext_vector_type(4))) short bf16x4;
typedef __attribute__((ext_vector_type(4))) float f32x4;

#define B_ 2
#define S_ 2048
#define H_ 16
#define D_ 64
#define BQ 128        // q rows per block (8 waves x 16)
#define BK 64         // keys per tile
#define LDK 72        // padded LDS row (144 B): keeps 16B align, stride 36 dwords = 4 mod 32
#define ROWSZ (H_ * D_)   // floats between consecutive s rows (1024)

__device__ __forceinline__ ushort f2bs(float f) {
    union { float f; unsigned u; } x; x.f = f;
    unsigned r = (x.u + 0x7FFFu + ((x.u >> 16) & 1u)) >> 16;
    return (ushort)r;
}

__device__ __forceinline__ unsigned pack2(float a, float b) {
#if __has_builtin(__builtin_amdgcn_cvt_pk_bf16_f32)
    typedef __attribute__((ext_vector_type(2))) __bf16 hwbf2;
    union { hwbf2 v; unsigned u; } x;
    x.v = __builtin_amdgcn_cvt_pk_bf16_f32(a, b);
    return x.u;
#else
    return (unsigned)f2bs(a) | ((unsigned)f2bs(b) << 16);
#endif
}

__device__ __forceinline__ float fexp2(float x) {
#if __has_builtin(__builtin_amdgcn_exp2f)
    return __builtin_amdgcn_exp2f(x);
#else
    return __expf(x * 0.69314718055994531f);
#endif
}

__device__ __forceinline__ f32x4 mfma16(bf16x4 a, bf16x4 b, f32x4 c) {
#if __has_builtin(__builtin_amdgcn_mfma_f32_16x16x16bf16_1k)
    return __builtin_amdgcn_mfma_f32_16x16x16bf16_1k(a, b, c, 0, 0, 0);
#else
    // zero-padded k: both operands use k=quad*8+j for j=0..3, zeros j=4..7 -> same result
    bf16x8 a8 = {a[0], a[1], a[2], a[3], 0, 0, 0, 0};
    bf16x8 b8 = {b[0], b[1], b[2], b[3], 0, 0, 0, 0};
    return __builtin_amdgcn_mfma_f32_16x16x32_bf16(a8, b8, c, 0, 0, 0);
#endif
}

__global__ __launch_bounds__(512, 4)
void fattn_kernel(const float* __restrict__ qg,
                  const float* __restrict__ kg,
                  const float* __restrict__ vg,
                  const float* __restrict__ maskg,
                  float* __restrict__ outg)
{
    __shared__ ushort Ks[BK * LDK];   // K tile, row=key, col=d (bf16)
    __shared__ ushort Vt[D_ * LDK];   // V tile transposed, row=d, col=key (bf16)

    const int qt = blockIdx.x;
    const int h  = blockIdx.y;
    const int b  = blockIdx.z;

    const int tid = threadIdx.x;
    const int w   = tid >> 6;          // wave 0..7, owns q rows w*16..w*16+15
    const int lane = tid & 63;
    const int g   = lane >> 4;         // quad 0..3
    const int l15 = lane & 15;         // q column within tile

    const size_t kvbase = (size_t)b * S_ * ROWSZ + h * D_;

    // ---- Q fragment (B-operand, x32): b[j] = Q[qrow][half*32 + g*8 + j] ----
    const int qrow = qt * BQ + w * 16 + l15;
    const float* qp = qg + (size_t)(b * S_ + qrow) * ROWSZ + h * D_;
    bf16x8 qf[2];
#pragma unroll
    for (int half = 0; half < 2; ++half) {
        float4 f0 = *(const float4*)(qp + half * 32 + g * 8);
        float4 f1 = *(const float4*)(qp + half * 32 + g * 8 + 4);
        union { bf16x8 v; uint4 u; } x;
        x.u = make_uint4(pack2(f0.x, f0.y), pack2(f0.z, f0.w),
                         pack2(f1.x, f1.y), pack2(f1.z, f1.w));
        qf[half] = x.v;
    }

    // staging maps
    const int skey16 = tid >> 4;       // 0..31: K-stage key (then +32)
    const int sd4    = (tid & 15) * 4; // K-stage d offset (float4)
    const int svd    = tid & 63;       // V-stage d
    const int svk8   = (tid >> 6) * 8; // V-stage key block of 8

    float m_r = -1e30f, l_r = 0.0f;    // per-lane (per q-column), log2 domain
    f32x4 o_acc[4];                    // O^T accumulator: d-tile t2, rows g*4+r
#pragma unroll
    for (int t = 0; t < 4; ++t) o_acc[t] = (f32x4){0.f, 0.f, 0.f, 0.f};

    const float SCALE2 = 0.125f * 1.44269504088896340736f;  // (1/sqrt(64)) * log2(e)
    const float LOG2E  = 1.44269504088896340736f;
    const float* maskb = maskg + (size_t)b * S_;

    for (int kt = 0; kt < S_ / BK; ++kt) {
        // ---- stage K row-major (coalesced float4, 2 keys/thread) ----
#pragma unroll
        for (int pass = 0; pass < 2; ++pass) {
            int key = skey16 + pass * 32;
            float4 f = *(const float4*)(kg + kvbase + (size_t)(kt * BK + key) * ROWSZ + sd4);
            *(uint2*)&Ks[key * LDK + sd4] = make_uint2(pack2(f.x, f.y), pack2(f.z, f.w));
        }
        // ---- stage V transposed (coalesced dword loads, vector b128 write) ----
        {
            float vv[8];
#pragma unroll
            for (int i = 0; i < 8; ++i)
                vv[i] = vg[kvbase + (size_t)(kt * BK + svk8 + i) * ROWSZ + svd];
            union { bf16x8 v; uint4 u; } x;
            x.u = make_uint4(pack2(vv[0], vv[1]), pack2(vv[2], vv[3]),
                             pack2(vv[4], vv[5]), pack2(vv[6], vv[7]));
            *(bf16x8*)&Vt[svd * LDK + svk8] = x.v;
        }
        __syncthreads();

        // ---- St = K Q^T : St[key=t*16+g*4+r][q=l15] in sacc[t][r] ----
        f32x4 sacc[4];
#pragma unroll
        for (int t = 0; t < 4; ++t) {
            f32x4 acc = (f32x4){0.f, 0.f, 0.f, 0.f};
            bf16x8 kf0 = *(const bf16x8*)&Ks[(t * 16 + l15) * LDK + 0  + g * 8];
            bf16x8 kf1 = *(const bf16x8*)&Ks[(t * 16 + l15) * LDK + 32 + g * 8];
            acc = __builtin_amdgcn_mfma_f32_16x16x32_bf16(kf0, qf[0], acc, 0, 0, 0);
            acc = __builtin_amdgcn_mfma_f32_16x16x32_bf16(kf1, qf[1], acc, 0, 0, 0);
            sacc[t] = acc;
        }

        // ---- scale + mask (log2 domain) ----
        float sv[4][4];
#pragma unroll
        for (int t = 0; t < 4; ++t) {
            float4 mk = *(const float4*)(maskb + kt * BK + t * 16 + g * 4);
            sv[t][0] = fmaf(mk.x, LOG2E, sacc[t][0] * SCALE2);
            sv[t][1] = fmaf(mk.y, LOG2E, sacc[t][1] * SCALE2);
            sv[t][2] = fmaf(mk.z, LOG2E, sacc[t][2] * SCALE2);
            sv[t][3] = fmaf(mk.w, LOG2E, sacc[t][3] * SCALE2);
        }

        // ---- online softmax, per-lane state (q = l15) ----
        float cm = sv[0][0];
#pragma unroll
        for (int t = 0; t < 4; ++t)
#pragma unroll
            for (int r = 0; r < 4; ++r) cm = fmaxf(cm, sv[t][r]);
        cm = fmaxf(cm, __shfl_xor(cm, 16));
        cm = fmaxf(cm, __shfl_xor(cm, 32));
        float newm = fmaxf(m_r, cm);
        float alpha = fexp2(m_r - newm);
        float rs = 0.f;
#pragma unroll
        for (int t = 0; t < 4; ++t)
#pragma unroll
            for (int r = 0; r < 4; ++r) {
                float p = fexp2(sv[t][r] - newm);
                sv[t][r] = p;
                rs += p;
            }
        rs += __shfl_xor(rs, 16);
        rs += __shfl_xor(rs, 32);
        l_r = l_r * alpha + rs;
        m_r = newm;
#pragma unroll
        for (int t = 0; t < 4; ++t) {
            o_acc[t][0] *= alpha; o_acc[t][1] *= alpha;
            o_acc[t][2] *= alpha; o_acc[t][3] *= alpha;
        }

        // ---- P^T fragments: St C-layout == x16 B-operand layout, direct from regs ----
        bf16x4 pf[4];
#pragma unroll
        for (int c = 0; c < 4; ++c) {
            union { bf16x4 v; uint2 u; } x;
            x.u = make_uint2(pack2(sv[c][0], sv[c][1]), pack2(sv[c][2], sv[c][3]));
            pf[c] = x.v;
        }

        // ---- O^T += V^T P^T (x16 MFMAs; A = V^T from d-major LDS, b64 reads) ----
#pragma unroll
        for (int t2 = 0; t2 < 4; ++t2)
#pragma unroll
            for (int c = 0; c < 4; ++c) {
                bf16x4 vf = *(const bf16x4*)&Vt[(t2 * 16 + l15) * LDK + c * 16 + g * 4];
                o_acc[t2] = mfma16(vf, pf[c], o_acc[t2]);
            }
        __syncthreads();
    }

    // ---- epilogue: O^T[d=t2*16+g*4+r][q=l15] / l -> out[b,qrow,h,d] fp32 ----
    const float inv = 1.0f / l_r;
    float* op = outg + (size_t)(b * S_ + qrow) * ROWSZ + h * D_;
#pragma unroll
    for (int t2 = 0; t2 < 4; ++t2)
#pragma unroll
        for (int r = 0; r < 4; ++r)
            op[t2 * 16 + g * 4 + r] = o_acc[t2][r] * inv;
}

extern "C" void kernel_launch(void* const* d_in, const int* in_sizes, int n_in,
                              void* d_out, int out_size, void* d_ws, size_t ws_size,
                              hipStream_t stream) {
    dim3 grid(S_ / BQ, H_, B_);   // (16,16,2) = 512 blocks, ~2/CU
    fattn_kernel<<<grid, dim3(512), 0, stream>>>(
        (const float*)d_in[0], (const float*)d_in[1], (const float*)d_in[2],
        (const float*)d_in[3], (float*)d_out);
}

// Round 4
// 155.146 us; speedup vs baseline: 1.7305x; 1.1319x over previous
//
#include <hip/hip_runtime.h>
#include <hip/hip_bf16.h>

// Round 4: S^T flash attention, fp32 in/out, bf16 MFMA.
//  - mask folded into QK MFMA C-init (pre-scaled by log2e in LDS)
//  - softmax scale folded into Q bf16 conversion
//  - packed cvt via __float22bfloat162_rn (v_cvt_pk_bf16_f32)
//  - reg-prefetch + LDS double buffer: 1 barrier/tile, global latency hidden
//  - swizzled V^T LDS layout: PV frags via 8 ds_read_b128 (was 16 b64)
//  - per-lane l partials, cross-lane reduced once in epilogue

typedef __attribute__((ext_vector_type(8))) short bf16x8;
typedef __attribute__((ext_vector_type(4))) short bf16x4;
typedef __attribute__((ext_vector_type(4))) float f32x4;

#define B_ 2
#define S_ 2048
#define H_ 16
#define D_ 64
#define BQ 128
#define BK 64
#define NT (S_ / BK)
#define LDK 72                 // padded LDS row (144 B)
#define ROWSZ (H_ * D_)        // 1024 floats between s rows

#define LOG2E  1.44269504088896340736f
#define SCALE2 (0.125f * LOG2E)

__device__ __forceinline__ unsigned pack2(float a, float b) {
    union { __hip_bfloat162 h; unsigned u; } x;
    x.h = __float22bfloat162_rn(make_float2(a, b));   // v_cvt_pk_bf16_f32
    return x.u;
}

__device__ __forceinline__ float fexp2(float x) {
#if __has_builtin(__builtin_amdgcn_exp2f)
    return __builtin_amdgcn_exp2f(x);
#else
    return __expf(x * 0.69314718055994531f);
#endif
}

__device__ __forceinline__ f32x4 mfma16(bf16x4 a, bf16x4 b, f32x4 c) {
#if __has_builtin(__builtin_amdgcn_mfma_f32_16x16x16bf16_1k)
    return __builtin_amdgcn_mfma_f32_16x16x16bf16_1k(a, b, c, 0, 0, 0);
#else
    bf16x8 a8 = {a[0], a[1], a[2], a[3], 0, 0, 0, 0};
    bf16x8 b8 = {b[0], b[1], b[2], b[3], 0, 0, 0, 0};
    return __builtin_amdgcn_mfma_f32_16x16x32_bf16(a8, b8, c, 0, 0, 0);
#endif
}

__global__ __launch_bounds__(512, 4)
void fattn_kernel(const float* __restrict__ qg,
                  const float* __restrict__ kg,
                  const float* __restrict__ vg,
                  const float* __restrict__ maskg,
                  float* __restrict__ outg)
{
    __shared__ __attribute__((aligned(16))) ushort Ks[2][BK * LDK];  // row=key, col=d
    __shared__ __attribute__((aligned(16))) ushort Vt[2][D_ * LDK];  // row=d, col=swizzled key
    __shared__ __attribute__((aligned(16))) float  Em[S_];           // mask * log2e

    const int qt = blockIdx.x, h = blockIdx.y, b = blockIdx.z;
    const int tid = threadIdx.x;
    const int w = tid >> 6, lane = tid & 63, g = lane >> 4, l15 = lane & 15;

    // ---- stage pre-scaled mask to LDS (once) ----
    {
        float4 mv = *(const float4*)(maskg + (size_t)b * S_ + tid * 4);
        *(float4*)&Em[tid * 4] = make_float4(mv.x * LOG2E, mv.y * LOG2E,
                                             mv.z * LOG2E, mv.w * LOG2E);
    }

    // ---- Q fragment (B-operand, x32), scale folded in ----
    const int qrow = qt * BQ + w * 16 + l15;
    const float* qp = qg + (size_t)(b * S_ + qrow) * ROWSZ + h * D_;
    bf16x8 qf[2];
#pragma unroll
    for (int half = 0; half < 2; ++half) {
        float4 f0 = *(const float4*)(qp + half * 32 + g * 8);
        float4 f1 = *(const float4*)(qp + half * 32 + g * 8 + 4);
        union { bf16x8 v; uint4 u; } x;
        x.u = make_uint4(pack2(f0.x * SCALE2, f0.y * SCALE2),
                         pack2(f0.z * SCALE2, f0.w * SCALE2),
                         pack2(f1.x * SCALE2, f1.y * SCALE2),
                         pack2(f1.z * SCALE2, f1.w * SCALE2));
        qf[half] = x.v;
    }

    // staging maps
    const int skey16 = tid >> 4;        // 0..31 (K rows; +32 for second)
    const int sd4    = (tid & 15) * 4;  // K d-offset (float4)
    const int svd    = lane;            // V: d = lane
    const int svk8   = w * 8;           // V: 8 keys per wave
    // swizzled V columns for this thread's two uint2 writes
    const int vc0 = (w >> 1) * 4 + 16 * ((2 * w) & 3);
    const int vc1 = (w >> 1) * 4 + 16 * ((2 * w + 1) & 3);

    const size_t kvbase = (size_t)b * S_ * ROWSZ + h * D_;

    float4 kpre0, kpre1;
    float  vpre[8];
    auto prefetch = [&](int kt) {
        const float* kb = kg + kvbase + (size_t)kt * BK * ROWSZ;
        kpre0 = *(const float4*)(kb + (size_t)skey16 * ROWSZ + sd4);
        kpre1 = *(const float4*)(kb + (size_t)(skey16 + 32) * ROWSZ + sd4);
        const float* vb = vg + kvbase + (size_t)kt * BK * ROWSZ + svd;
#pragma unroll
        for (int i = 0; i < 8; ++i) vpre[i] = vb[(size_t)(svk8 + i) * ROWSZ];
    };
    auto stage = [&](int buf) {
        *(uint2*)&Ks[buf][skey16 * LDK + sd4] =
            make_uint2(pack2(kpre0.x, kpre0.y), pack2(kpre0.z, kpre0.w));
        *(uint2*)&Ks[buf][(skey16 + 32) * LDK + sd4] =
            make_uint2(pack2(kpre1.x, kpre1.y), pack2(kpre1.z, kpre1.w));
        *(uint2*)&Vt[buf][svd * LDK + vc0] =
            make_uint2(pack2(vpre[0], vpre[1]), pack2(vpre[2], vpre[3]));
        *(uint2*)&Vt[buf][svd * LDK + vc1] =
            make_uint2(pack2(vpre[4], vpre[5]), pack2(vpre[6], vpre[7]));
    };

    float m_r = -1e30f, l_r = 0.0f;     // per-lane (q = l15), log2 domain
    f32x4 o_acc[4];
#pragma unroll
    for (int t = 0; t < 4; ++t) o_acc[t] = (f32x4){0.f, 0.f, 0.f, 0.f};

    prefetch(0);
    stage(0);
    __syncthreads();                    // also covers Em staging

    for (int kt = 0; kt < NT; ++kt) {
        const int cur = kt & 1;
        if (kt + 1 < NT) prefetch(kt + 1);   // loads in flight across compute

        // ---- St = K Q^T + mask (C-init) : St[key=t*16+g*4+r][q=l15] ----
        const ushort* ks = Ks[cur];
        float sv[4][4];
#pragma unroll
        for (int t = 0; t < 4; ++t) {
            f32x4 acc = *(const f32x4*)&Em[kt * BK + t * 16 + g * 4];  // broadcast
            bf16x8 kf0 = *(const bf16x8*)&ks[(t * 16 + l15) * LDK + g * 8];
            bf16x8 kf1 = *(const bf16x8*)&ks[(t * 16 + l15) * LDK + 32 + g * 8];
            acc = __builtin_amdgcn_mfma_f32_16x16x32_bf16(kf0, qf[0], acc, 0, 0, 0);
            acc = __builtin_amdgcn_mfma_f32_16x16x32_bf16(kf1, qf[1], acc, 0, 0, 0);
            sv[t][0] = acc[0]; sv[t][1] = acc[1]; sv[t][2] = acc[2]; sv[t][3] = acc[3];
        }

        // ---- online softmax (per-lane state; only max needs cross-lane) ----
        float cm = sv[0][0];
#pragma unroll
        for (int t = 0; t < 4; ++t)
#pragma unroll
            for (int r = 0; r < 4; ++r) cm = fmaxf(cm, sv[t][r]);
        cm = fmaxf(cm, __shfl_xor(cm, 16));
        cm = fmaxf(cm, __shfl_xor(cm, 32));
        const float newm = fmaxf(m_r, cm);
        const float alpha = fexp2(m_r - newm);
        float rs = 0.f;
#pragma unroll
        for (int t = 0; t < 4; ++t)
#pragma unroll
            for (int r = 0; r < 4; ++r) {
                float p = fexp2(sv[t][r] - newm);
                sv[t][r] = p;
                rs += p;
            }
        l_r = l_r * alpha + rs;         // per-lane partial; reduced in epilogue
        m_r = newm;
#pragma unroll
        for (int t = 0; t < 4; ++t) {
            o_acc[t][0] *= alpha; o_acc[t][1] *= alpha;
            o_acc[t][2] *= alpha; o_acc[t][3] *= alpha;
        }

        // ---- P^T fragments direct from regs (St C-layout == x16 B-layout) ----
        bf16x4 pf[4];
#pragma unroll
        for (int c = 0; c < 4; ++c) {
            union { bf16x4 v; uint2 u; } x;
            x.u = make_uint2(pack2(sv[c][0], sv[c][1]), pack2(sv[c][2], sv[c][3]));
            pf[c] = x.v;
        }

        // ---- O^T += V^T P^T : swizzled Vt gives both c-halves in one b128 ----
        const ushort* vt = Vt[cur];
#pragma unroll
        for (int t2 = 0; t2 < 4; ++t2) {
#pragma unroll
            for (int c2 = 0; c2 < 2; ++c2) {
                bf16x8 vv = *(const bf16x8*)&vt[(t2 * 16 + l15) * LDK + g * 16 + c2 * 8];
                bf16x4 vlo = {vv[0], vv[1], vv[2], vv[3]};
                bf16x4 vhi = {vv[4], vv[5], vv[6], vv[7]};
                o_acc[t2] = mfma16(vlo, pf[2 * c2],     o_acc[t2]);
                o_acc[t2] = mfma16(vhi, pf[2 * c2 + 1], o_acc[t2]);
            }
        }

        if (kt + 1 < NT) stage(cur ^ 1);    // vmcnt wait lands here, post-compute
        __syncthreads();                    // single barrier per tile
    }

    // ---- epilogue ----
    l_r += __shfl_xor(l_r, 16);
    l_r += __shfl_xor(l_r, 32);
    const float inv = 1.0f / l_r;
    float* op = outg + (size_t)(b * S_ + qrow) * ROWSZ + h * D_;
#pragma unroll
    for (int t2 = 0; t2 < 4; ++t2)
#pragma unroll
        for (int r = 0; r < 4; ++r)
            op[t2 * 16 + g * 4 + r] = o_acc[t2][r] * inv;
}

extern "C" void kernel_launch(void* const* d_in, const int* in_sizes, int n_in,
                              void* d_out, int out_size, void* d_ws, size_t ws_size,
                              hipStream_t stream) {
    dim3 grid(S_ / BQ, H_, B_);   // (16,16,2) = 512 blocks
    fattn_kernel<<<grid, dim3(512), 0, stream>>>(
        (const float*)d_in[0], (const float*)d_in[1], (const float*)d_in[2],
        (const float*)d_in[3], (float*)d_out);
}